// Round 4
// baseline (207.827 us; speedup 1.0000x reference)
//
#include <hip/hip_runtime.h>
#include <stdint.h>

#define NH 16
#define NN 4096

typedef __attribute__((ext_vector_type(8))) short bf16x8;
typedef __attribute__((ext_vector_type(4))) short bf16x4;
typedef __attribute__((ext_vector_type(4))) float f32x4;
typedef __attribute__((ext_vector_type(16))) float f32x16;
typedef unsigned short u16;
typedef unsigned int u32;
typedef __attribute__((ext_vector_type(4))) u32 u32x4;

__device__ __forceinline__ u16 f2bf(float f) {
  u32 u = __float_as_uint(f);
  return (u16)((u + 0x7FFFu + ((u >> 16) & 1u)) >> 16);
}

#define GLD16(gp, lp)                                              \
  __builtin_amdgcn_global_load_lds(                                \
      (__attribute__((address_space(1))) void*)(gp),               \
      (__attribute__((address_space(3))) void*)(lp), 16, 0, 0)

// ---------------- elementwise f32 -> bf16 ----------------
__global__ __launch_bounds__(256) void cvt_bf16_kernel(const float* __restrict__ src,
                                                       u16* __restrict__ dst, int n) {
  int i = (blockIdx.x * blockDim.x + threadIdx.x) * 8;
  if (i >= n) return;
  float4 a = *(const float4*)(src + i);
  float4 b = *(const float4*)(src + i + 4);
  uint4 o;
  o.x = (u32)f2bf(a.x) | ((u32)f2bf(a.y) << 16);
  o.y = (u32)f2bf(a.z) | ((u32)f2bf(a.w) << 16);
  o.z = (u32)f2bf(b.x) | ((u32)f2bf(b.y) << 16);
  o.w = (u32)f2bf(b.z) | ((u32)f2bf(b.w) << 16);
  *(uint4*)(dst + i) = o;
}

// ---------------- fused 4x transpose + cvt: W[k][n] f32 -> Wt[n][k] bf16 ----------------
__global__ __launch_bounds__(256) void transpose4(const float* __restrict__ Wq,
                                                  const float* __restrict__ Wk,
                                                  const float* __restrict__ Wv,
                                                  const float* __restrict__ Wo,
                                                  u16* __restrict__ Wqt, u16* __restrict__ Wkt,
                                                  u16* __restrict__ Wvt, u16* __restrict__ Wot) {
  __shared__ float tile[64][65];
  const float* src;
  u16* dst;
  float scale = 1.0f;
  int z = blockIdx.z;
  if (z == 0) { src = Wq; dst = Wqt; scale = 0.125f * 1.4426950408889634f; }
  else if (z == 1) { src = Wk; dst = Wkt; }
  else if (z == 2) { src = Wv; dst = Wvt; }
  else { src = Wo; dst = Wot; }
  int tx = threadIdx.x & 63, ty = threadIdx.x >> 6;
  int c0 = blockIdx.x * 64, r0 = blockIdx.y * 64;
#pragma unroll
  for (int i = ty; i < 64; i += 4)
    tile[i][tx] = src[(size_t)(r0 + i) * 1024 + c0 + tx];
  __syncthreads();
#pragma unroll
  for (int i = ty; i < 64; i += 4)
    dst[(size_t)(c0 + i) * 1024 + r0 + tx] = f2bf(tile[tx][i] * scale);
}

// ---------------- fused QKV GEMM: [4096][1024] @ Wt[3072][1024]^T ----------------
__global__ __launch_bounds__(256) void gemm_qkv(const u16* __restrict__ A,
                                                const u16* __restrict__ Bt,
                                                u16* __restrict__ Qb, u16* __restrict__ Kb,
                                                u16* __restrict__ Vth) {
  __shared__ __align__(16) u16 A_lds[2][128 * 32];
  __shared__ __align__(16) u16 B_lds[2][128 * 32];
  const int tid = threadIdx.x;
  const int l = tid & 63, w = tid >> 6;
  const int g = l >> 4, c = l & 15;
  const int wr = w >> 1, wc = w & 1;
  const int m0 = blockIdx.y * 128, n0 = blockIdx.x * 128;

  const int srow = tid >> 2;
  const u32 sswz = (u32)(((tid & 3) * 16) ^ ((srow & 3) << 4));
  const char* Ag = (const char*)A + (size_t)(m0 + srow) * 2048 + sswz;
  const char* Bg = (const char*)Bt + (size_t)(n0 + srow) * 2048 + sswz;
  const u32 ldsb = (u32)(w * 1024);

#define GSTAGE(buf, ks_)                                                          \
  do {                                                                            \
    u32 koff_ = (u32)(ks_) * 64;                                                  \
    _Pragma("unroll") for (int p_ = 0; p_ < 2; ++p_) {                            \
      GLD16(Ag + koff_ + (size_t)p_ * 64 * 2048,                                  \
            (char*)A_lds[buf] + p_ * 4096 + ldsb);                                \
      GLD16(Bg + koff_ + (size_t)p_ * 64 * 2048,                                  \
            (char*)B_lds[buf] + p_ * 4096 + ldsb);                                \
    }                                                                             \
  } while (0)

  f32x4 acc[4][4];
#pragma unroll
  for (int i = 0; i < 4; ++i)
#pragma unroll
    for (int j = 0; j < 4; ++j) acc[i][j] = (f32x4){0.f, 0.f, 0.f, 0.f};

  int cur = 0;
  GSTAGE(0, 0);
  for (int ks = 0; ks < 32; ++ks) {
    GSTAGE(cur ^ 1, (ks + 1) & 31);
    asm volatile("s_waitcnt vmcnt(4)" ::: "memory");
    __builtin_amdgcn_s_barrier();
    __builtin_amdgcn_sched_barrier(0);
    const char* Ac = (const char*)A_lds[cur];
    const char* Bc = (const char*)B_lds[cur];
    bf16x8 af[4], bfr[4];
#pragma unroll
    for (int i = 0; i < 4; ++i) {
      int row = wr * 64 + i * 16 + c;
      af[i] = *(const bf16x8*)(Ac + row * 64 + ((g * 16) ^ ((row & 3) << 4)));
    }
#pragma unroll
    for (int j = 0; j < 4; ++j) {
      int row = wc * 64 + j * 16 + c;
      bfr[j] = *(const bf16x8*)(Bc + row * 64 + ((g * 16) ^ ((row & 3) << 4)));
    }
    __builtin_amdgcn_s_setprio(1);
#pragma unroll
    for (int i = 0; i < 4; ++i)
#pragma unroll
      for (int j = 0; j < 4; ++j)
        acc[i][j] = __builtin_amdgcn_mfma_f32_16x16x32_bf16(af[i], bfr[j], acc[i][j], 0, 0, 0);
    __builtin_amdgcn_s_setprio(0);
    asm volatile("s_waitcnt lgkmcnt(0)" ::: "memory");
    __builtin_amdgcn_s_barrier();
    __builtin_amdgcn_sched_barrier(0);
    cur ^= 1;
  }
#undef GSTAGE

  const int sec = n0 >> 10;  // block-uniform: 0=Q, 1=K, 2=V
#pragma unroll
  for (int i = 0; i < 4; ++i)
#pragma unroll
    for (int j = 0; j < 4; ++j)
#pragma unroll
      for (int r = 0; r < 4; ++r) {
        int m = m0 + wr * 64 + i * 16 + g * 4 + r;
        int col = n0 + wc * 64 + j * 16 + c;
        int cc = col & 1023;
        u16 v = f2bf(acc[i][j][r]);
        if (sec == 0) Qb[(size_t)m * 1024 + cc] = v;
        else if (sec == 1) Kb[(size_t)m * 1024 + cc] = v;
        else Vth[(size_t)cc * 4096 + m] = v;  // cc = h*64+d
      }
}

// ---------------- out-proj GEMM, 64x64 tiles ----------------
__global__ __launch_bounds__(256) void gemm_out64(const u16* __restrict__ A,
                                                  const u16* __restrict__ Bt,
                                                  float* __restrict__ out,
                                                  const float* __restrict__ bias) {
  __shared__ __align__(16) u16 A_lds[2][64 * 32];
  __shared__ __align__(16) u16 B_lds[2][64 * 32];
  const int tid = threadIdx.x;
  const int l = tid & 63, w = tid >> 6;
  const int g = l >> 4, c = l & 15;
  const int wr = w >> 1, wc = w & 1;
  const int m0 = blockIdx.y * 64, n0 = blockIdx.x * 64;

  const int srow = tid >> 2;
  const u32 sswz = (u32)(((tid & 3) * 16) ^ ((srow & 3) << 4));
  const char* Ag = (const char*)A + (size_t)(m0 + srow) * 2048 + sswz;
  const char* Bg = (const char*)Bt + (size_t)(n0 + srow) * 2048 + sswz;
  const u32 ldsb = (u32)(w * 1024);

#define GSTAGE2(buf, ks_)                                                         \
  do {                                                                            \
    u32 koff_ = (u32)(ks_) * 64;                                                  \
    GLD16(Ag + koff_, (char*)A_lds[buf] + ldsb);                                  \
    GLD16(Bg + koff_, (char*)B_lds[buf] + ldsb);                                  \
  } while (0)

  f32x4 acc[2][2];
#pragma unroll
  for (int i = 0; i < 2; ++i)
#pragma unroll
    for (int j = 0; j < 2; ++j) acc[i][j] = (f32x4){0.f, 0.f, 0.f, 0.f};

  int cur = 0;
  GSTAGE2(0, 0);
  for (int ks = 0; ks < 32; ++ks) {
    GSTAGE2(cur ^ 1, (ks + 1) & 31);
    asm volatile("s_waitcnt vmcnt(2)" ::: "memory");
    __builtin_amdgcn_s_barrier();
    __builtin_amdgcn_sched_barrier(0);
    const char* Ac = (const char*)A_lds[cur];
    const char* Bc = (const char*)B_lds[cur];
    bf16x8 af[2], bfr[2];
#pragma unroll
    for (int i = 0; i < 2; ++i) {
      int row = wr * 32 + i * 16 + c;
      af[i] = *(const bf16x8*)(Ac + row * 64 + ((g * 16) ^ ((row & 3) << 4)));
    }
#pragma unroll
    for (int j = 0; j < 2; ++j) {
      int row = wc * 32 + j * 16 + c;
      bfr[j] = *(const bf16x8*)(Bc + row * 64 + ((g * 16) ^ ((row & 3) << 4)));
    }
    __builtin_amdgcn_s_setprio(1);
#pragma unroll
    for (int i = 0; i < 2; ++i)
#pragma unroll
      for (int j = 0; j < 2; ++j)
        acc[i][j] = __builtin_amdgcn_mfma_f32_16x16x32_bf16(af[i], bfr[j], acc[i][j], 0, 0, 0);
    __builtin_amdgcn_s_setprio(0);
    asm volatile("s_waitcnt lgkmcnt(0)" ::: "memory");
    __builtin_amdgcn_s_barrier();
    __builtin_amdgcn_sched_barrier(0);
    cur ^= 1;
  }
#undef GSTAGE2

#pragma unroll
  for (int i = 0; i < 2; ++i)
#pragma unroll
    for (int j = 0; j < 2; ++j)
#pragma unroll
      for (int r = 0; r < 4; ++r) {
        int m = m0 + wr * 32 + i * 16 + g * 4 + r;
        int col = n0 + wc * 32 + j * 16 + c;
        out[(size_t)m * 1024 + col] = acc[i][j][r] + bias[col];
      }
}

// ---------------- flash attention, swapped-QK^T 32x32, no-max exp2 softmax ----------------
// SPLIT=1: blockIdx.z selects KV half; unnormalized f32 partials -> Op, row-sums -> Lp.
// SPLIT=0: full KV range, normalized bf16 -> Ob.
template <int SPLIT>
__global__ __launch_bounds__(256) void flash_attn_t(const u16* __restrict__ Qb,
                                                    const u16* __restrict__ Kb,
                                                    const u16* __restrict__ Vt,
                                                    u16* __restrict__ Ob,
                                                    float* __restrict__ Op,
                                                    float* __restrict__ Lp) {
  constexpr int NT = SPLIT ? 32 : 64;  // KV tiles per block
  __shared__ __align__(16) u16 K_lds[2][64 * 64];
  __shared__ __align__(16) u16 V_lds[2][64 * 64];
  const int tid = threadIdx.x;
  const int l = tid & 63, w = tid >> 6;
  const int lq = l & 31, hi = l >> 5;
  const int h = blockIdx.y;
  const int z = SPLIT ? blockIdx.z : 0;
  const int kb = z * 32;  // KV tile base
  const int q = blockIdx.x * 128 + w * 32 + lq;

  bf16x8 qf[4];
  const u16* qrow = Qb + (size_t)q * 1024 + h * 64;
#pragma unroll
  for (int dm = 0; dm < 4; ++dm) qf[dm] = *(const bf16x8*)(qrow + dm * 16 + hi * 8);

  f32x16 ot[2];
#pragma unroll
  for (int a = 0; a < 2; ++a)
#pragma unroll
    for (int r = 0; r < 16; ++r) ot[a][r] = 0.f;
  float lrow = 0.f;
  f32x16 stA[2], stB[2];

  const int srow = tid >> 3;
  const u32 sswz = (u32)(((tid & 7) * 16) ^ ((srow & 7) << 4));
  const char* Kg = (const char*)Kb + ((size_t)srow * 1024 + h * 64) * 2 + sswz;
  const char* Vg = (const char*)Vt + ((size_t)(h * 64 + srow) * 4096) * 2 + sswz;
  const u32 ldsb = (u32)(w * 1024);

#define CONSUME(STP, VSLOT)                                                       \
  {                                                                               \
    const char* Vp_ = (const char*)(VSLOT);                                       \
    u32 pk[16];                                                                   \
    float rsum = 0.f;                                                             \
    _Pragma("unroll") for (int s_ = 0; s_ < 2; ++s_)                              \
    _Pragma("unroll") for (int j_ = 0; j_ < 8; ++j_) {                            \
      float p0_ = __builtin_amdgcn_exp2f(STP[s_][2 * j_]);                        \
      float p1_ = __builtin_amdgcn_exp2f(STP[s_][2 * j_ + 1]);                    \
      rsum += p0_ + p1_;                                                          \
      u32 wpk_;                                                                   \
      asm("v_cvt_pk_bf16_f32 %0, %1, %2" : "=v"(wpk_) : "v"(p0_), "v"(p1_));      \
      pk[s_ * 8 + j_] = wpk_;                                                     \
    }                                                                             \
    lrow += rsum;                                                                 \
    __builtin_amdgcn_s_setprio(1);                                                \
    _Pragma("unroll") for (int sti_ = 0; sti_ < 4; ++sti_) {                      \
      u32x4 pw_ = {pk[sti_ * 4 + 0], pk[sti_ * 4 + 1], pk[sti_ * 4 + 2],          \
                   pk[sti_ * 4 + 3]};                                             \
      bf16x8 pfrag_ = __builtin_bit_cast(bf16x8, pw_);                            \
      const u32 cb_ = (u32)(sti_ * 32 + hi * 8);                                  \
      _Pragma("unroll") for (int a_ = 0; a_ < 2; ++a_) {                          \
        const int rowd_ = a_ * 32 + lq;                                           \
        const u32 rs_ = (u32)(rowd_ * 128), rz_ = (u32)((rowd_ & 7) << 4);        \
        bf16x4 v0_ = *(const bf16x4*)(Vp_ + rs_ + (cb_ ^ rz_));                   \
        bf16x4 v1_ = *(const bf16x4*)(Vp_ + rs_ + ((cb_ + 16) ^ rz_));            \
        bf16x8 vf_ = __builtin_shufflevector(v0_, v1_, 0, 1, 2, 3, 4, 5, 6, 7);   \
        ot[a_] = __builtin_amdgcn_mfma_f32_32x32x16_bf16(vf_, pfrag_, ot[a_], 0, 0, 0); \
      }                                                                           \
    }                                                                             \
    __builtin_amdgcn_s_setprio(0);                                                \
  }

#define BODY(TI, STC, STP, DOPREV)                                                \
  {                                                                               \
    const int ti_ = (TI);                                                         \
    const int nxt_ = (ti_ + 1) & (NT - 1);                                        \
    {                                                                             \
      const char* kg_ = Kg + (size_t)(kb + nxt_) * 64 * 2048;                     \
      char* kl_ = (char*)K_lds[nxt_ & 1] + ldsb;                                  \
      GLD16(kg_, kl_);                                                            \
      GLD16(kg_ + 32 * 2048, kl_ + 4096);                                         \
      const char* vg_ = Vg + (size_t)(kb + ti_) * 128;                            \
      char* vl_ = (char*)V_lds[ti_ & 1] + ldsb;                                   \
      GLD16(vg_, vl_);                                                            \
      GLD16(vg_ + (size_t)32 * 8192, vl_ + 4096);                                 \
    }                                                                             \
    asm volatile("s_waitcnt vmcnt(4)" ::: "memory");                              \
    __builtin_amdgcn_s_barrier();                                                 \
    __builtin_amdgcn_sched_barrier(0);                                            \
    const char* Kc_ = (const char*)K_lds[ti_ & 1];                                \
    _Pragma("unroll") for (int s_ = 0; s_ < 2; ++s_)                              \
    _Pragma("unroll") for (int r_ = 0; r_ < 16; ++r_) STC[s_][r_] = 0.f;          \
    __builtin_amdgcn_s_setprio(1);                                                \
    _Pragma("unroll") for (int s_ = 0; s_ < 2; ++s_) {                            \
      const int row_ = s_ * 32 + lq;                                              \
      const u32 rs_ = (u32)(row_ * 128), rz_ = (u32)((row_ & 7) << 4);            \
      _Pragma("unroll") for (int dm_ = 0; dm_ < 4; ++dm_) {                       \
        bf16x8 kf_ = *(const bf16x8*)(Kc_ + rs_ + ((u32)(dm_ * 32 + hi * 16) ^ rz_)); \
        STC[s_] = __builtin_amdgcn_mfma_f32_32x32x16_bf16(kf_, qf[dm_], STC[s_], 0, 0, 0); \
      }                                                                           \
    }                                                                             \
    __builtin_amdgcn_s_setprio(0);                                                \
    if (DOPREV) CONSUME(STP, V_lds[(ti_ - 1) & 1]);                               \
    asm volatile("s_waitcnt lgkmcnt(0)" ::: "memory");                            \
    __builtin_amdgcn_s_barrier();                                                 \
    __builtin_amdgcn_sched_barrier(0);                                            \
  }

  {  // prologue: stage K(kb)
    const char* kg0 = Kg + (size_t)kb * 64 * 2048;
    char* kl = (char*)K_lds[0] + ldsb;
    GLD16(kg0, kl);
    GLD16(kg0 + 32 * 2048, kl + 4096);
  }

  BODY(0, stA, stA, 0);
  for (int i = 1; i < NT - 1; i += 2) {
    BODY(i, stB, stA, 1);
    BODY(i + 1, stA, stB, 1);
  }
  BODY(NT - 1, stB, stA, 1);
  asm volatile("s_waitcnt vmcnt(0)" ::: "memory");
  __builtin_amdgcn_s_barrier();
  __builtin_amdgcn_sched_barrier(0);
  CONSUME(stB, V_lds[(NT - 1) & 1]);

#undef BODY
#undef CONSUME

  lrow += __shfl_xor(lrow, 32, 64);
  if constexpr (SPLIT) {
    float* orow = Op + (size_t)z * (4096 * 1024) + (size_t)q * 1024 + h * 64 + hi * 4;
#pragma unroll
    for (int a = 0; a < 2; ++a)
#pragma unroll
      for (int rr = 0; rr < 4; ++rr) {
        float4 fv = {ot[a][rr * 4 + 0], ot[a][rr * 4 + 1], ot[a][rr * 4 + 2],
                     ot[a][rr * 4 + 3]};
        *(float4*)(orow + a * 32 + rr * 8) = fv;
      }
    if (hi == 0) Lp[z * 65536 + h * 4096 + q] = lrow;
  } else {
    float inv = 1.f / lrow;
    u16* orow = Ob + (size_t)q * 1024 + h * 64 + hi * 4;
#pragma unroll
    for (int a = 0; a < 2; ++a)
#pragma unroll
      for (int rr = 0; rr < 4; ++rr) {
        ushort4 o4;
        o4.x = f2bf(ot[a][rr * 4 + 0] * inv);
        o4.y = f2bf(ot[a][rr * 4 + 1] * inv);
        o4.z = f2bf(ot[a][rr * 4 + 2] * inv);
        o4.w = f2bf(ot[a][rr * 4 + 3] * inv);
        *(ushort4*)(orow + a * 32 + rr * 8) = o4;
      }
  }
}

// ---------------- merge KV halves: Ob = (O0+O1)/(L0+L1), f32 -> bf16 ----------------
__global__ __launch_bounds__(256) void merge_halves(const float* __restrict__ O0,
                                                    const float* __restrict__ O1,
                                                    const float* __restrict__ L0,
                                                    const float* __restrict__ L1,
                                                    u16* __restrict__ Ob) {
  int idx = blockIdx.x * 256 + threadIdx.x;  // 8 cols each
  int q = idx >> 7;
  int c0 = (idx & 127) * 8;
  int h = c0 >> 6;
  float inv = 1.f / (L0[h * 4096 + q] + L1[h * 4096 + q]);
  size_t off = (size_t)q * 1024 + c0;
  float4 a0 = *(const float4*)(O0 + off), a1 = *(const float4*)(O0 + off + 4);
  float4 b0 = *(const float4*)(O1 + off), b1 = *(const float4*)(O1 + off + 4);
  ushort4 o0, o1;
  o0.x = f2bf((a0.x + b0.x) * inv);
  o0.y = f2bf((a0.y + b0.y) * inv);
  o0.z = f2bf((a0.z + b0.z) * inv);
  o0.w = f2bf((a0.w + b0.w) * inv);
  o1.x = f2bf((a1.x + b1.x) * inv);
  o1.y = f2bf((a1.y + b1.y) * inv);
  o1.z = f2bf((a1.z + b1.z) * inv);
  o1.w = f2bf((a1.w + b1.w) * inv);
  *(ushort4*)(Ob + off) = o0;
  *(ushort4*)(Ob + off + 4) = o1;
}

extern "C" void kernel_launch(void* const* d_in, const int* in_sizes, int n_in,
                              void* d_out, int out_size, void* d_ws, size_t ws_size,
                              hipStream_t stream) {
  const float* x = (const float*)d_in[0];
  const float* Wq = (const float*)d_in[1];
  const float* Wk = (const float*)d_in[2];
  const float* Wv = (const float*)d_in[3];
  const float* Wo = (const float*)d_in[4];
  const float* bo = (const float*)d_in[5];
  float* out = (float*)d_out;

  char* ws = (char*)d_ws;
  u16* xb  = (u16*)(ws);                  // 8 MB (dead after gemm_qkv; reused as ObM)
  u16* Wqt = (u16*)(ws + (8u << 20));     // 2 MB  [Wqt|Wkt|Wvt] contiguous
  u16* Wot = (u16*)(ws + (14u << 20));    // 2 MB
  u16* Qb  = (u16*)(ws + (16u << 20));    // 8 MB
  u16* Kbf = (u16*)(ws + (24u << 20));    // 8 MB
  u16* Vth = (u16*)(ws + (32u << 20));    // 8 MB  [h][64][n]
  u16* Ob  = (u16*)(ws + (40u << 20));    // 8 MB (fallback path output)
  float* Op = (float*)(ws + (40u << 20)); // 32 MB (split path: 2x f32 partials)
  float* Lp = (float*)(ws + (72u << 20)); // 512 KB (2x16x4096 f32)
  u16* Wkt = Wqt + (1u << 20);
  u16* Wvt = Wqt + (2u << 20);

  const bool split = ws_size >= ((73u << 20) + (1u << 19));

  cvt_bf16_kernel<<<2048, 256, 0, stream>>>(x, xb, 4096 * 1024);
  transpose4<<<dim3(16, 16, 4), 256, 0, stream>>>(Wq, Wk, Wv, Wo, Wqt, Wkt, Wvt, Wot);
  gemm_qkv<<<dim3(24, 32), 256, 0, stream>>>(xb, Wqt, Qb, Kbf, Vth);

  if (split) {
    flash_attn_t<1><<<dim3(32, 16, 2), 256, 0, stream>>>(Qb, Kbf, Vth, nullptr, Op, Lp);
    u16* ObM = (u16*)ws;  // reuse xb region
    merge_halves<<<2048, 256, 0, stream>>>(Op, Op + (1u << 22), Lp, Lp + 65536, ObM);
    gemm_out64<<<dim3(16, 64), 256, 0, stream>>>(ObM, Wot, out, bo);
  } else {
    flash_attn_t<0><<<dim3(32, 16, 1), 256, 0, stream>>>(Qb, Kbf, Vth, Ob, nullptr, nullptr);
    gemm_out64<<<dim3(16, 64), 256, 0, stream>>>(Ob, Wot, out, bo);
  }
}

// Round 5
// 201.543 us; speedup vs baseline: 1.0312x; 1.0312x over previous
//
#include <hip/hip_runtime.h>
#include <stdint.h>

#define NH 16
#define NN 4096

typedef __attribute__((ext_vector_type(8))) short bf16x8;
typedef __attribute__((ext_vector_type(4))) short bf16x4;
typedef __attribute__((ext_vector_type(4))) float f32x4;
typedef __attribute__((ext_vector_type(16))) float f32x16;
typedef unsigned short u16;
typedef unsigned int u32;
typedef __attribute__((ext_vector_type(4))) u32 u32x4;

__device__ __forceinline__ u16 f2bf(float f) {
  u32 u = __float_as_uint(f);
  return (u16)((u + 0x7FFFu + ((u >> 16) & 1u)) >> 16);
}

#define GLD16(gp, lp)                                              \
  __builtin_amdgcn_global_load_lds(                                \
      (__attribute__((address_space(1))) void*)(gp),               \
      (__attribute__((address_space(3))) void*)(lp), 16, 0, 0)

// ---------------- elementwise f32 -> bf16 ----------------
__global__ __launch_bounds__(256) void cvt_bf16_kernel(const float* __restrict__ src,
                                                       u16* __restrict__ dst, int n) {
  int i = (blockIdx.x * blockDim.x + threadIdx.x) * 8;
  if (i >= n) return;
  float4 a = *(const float4*)(src + i);
  float4 b = *(const float4*)(src + i + 4);
  uint4 o;
  o.x = (u32)f2bf(a.x) | ((u32)f2bf(a.y) << 16);
  o.y = (u32)f2bf(a.z) | ((u32)f2bf(a.w) << 16);
  o.z = (u32)f2bf(b.x) | ((u32)f2bf(b.y) << 16);
  o.w = (u32)f2bf(b.z) | ((u32)f2bf(b.w) << 16);
  *(uint4*)(dst + i) = o;
}

// ---------------- fused 4x transpose + cvt: W[k][n] f32 -> Wt[n][k] bf16 ----------------
__global__ __launch_bounds__(256) void transpose4(const float* __restrict__ Wq,
                                                  const float* __restrict__ Wk,
                                                  const float* __restrict__ Wv,
                                                  const float* __restrict__ Wo,
                                                  u16* __restrict__ Wqt, u16* __restrict__ Wkt,
                                                  u16* __restrict__ Wvt, u16* __restrict__ Wot) {
  __shared__ float tile[64][65];
  const float* src;
  u16* dst;
  float scale = 1.0f;
  int z = blockIdx.z;
  if (z == 0) { src = Wq; dst = Wqt; scale = 0.125f * 1.4426950408889634f; }
  else if (z == 1) { src = Wk; dst = Wkt; }
  else if (z == 2) { src = Wv; dst = Wvt; }
  else { src = Wo; dst = Wot; }
  int tx = threadIdx.x & 63, ty = threadIdx.x >> 6;
  int c0 = blockIdx.x * 64, r0 = blockIdx.y * 64;
#pragma unroll
  for (int i = ty; i < 64; i += 4)
    tile[i][tx] = src[(size_t)(r0 + i) * 1024 + c0 + tx];
  __syncthreads();
#pragma unroll
  for (int i = ty; i < 64; i += 4)
    dst[(size_t)(c0 + i) * 1024 + r0 + tx] = f2bf(tile[tx][i] * scale);
}

// ---------------- fused QKV GEMM: [4096][1024] @ Wt[3072][1024]^T ----------------
// V (sec==2) is stored with n-within-16 quads interleaved [0,2,1,3] so flash PV
// can read each A-fragment as a single b128.
__global__ __launch_bounds__(256) void gemm_qkv(const u16* __restrict__ A,
                                                const u16* __restrict__ Bt,
                                                u16* __restrict__ Qb, u16* __restrict__ Kb,
                                                u16* __restrict__ Vth) {
  __shared__ __align__(16) u16 A_lds[2][128 * 32];
  __shared__ __align__(16) u16 B_lds[2][128 * 32];
  const int tid = threadIdx.x;
  const int l = tid & 63, w = tid >> 6;
  const int g = l >> 4, c = l & 15;
  const int wr = w >> 1, wc = w & 1;
  const int m0 = blockIdx.y * 128, n0 = blockIdx.x * 128;

  const int srow = tid >> 2;
  const u32 sswz = (u32)(((tid & 3) * 16) ^ ((srow & 3) << 4));
  const char* Ag = (const char*)A + (size_t)(m0 + srow) * 2048 + sswz;
  const char* Bg = (const char*)Bt + (size_t)(n0 + srow) * 2048 + sswz;
  const u32 ldsb = (u32)(w * 1024);

#define GSTAGE(buf, ks_)                                                          \
  do {                                                                            \
    u32 koff_ = (u32)(ks_) * 64;                                                  \
    _Pragma("unroll") for (int p_ = 0; p_ < 2; ++p_) {                            \
      GLD16(Ag + koff_ + (size_t)p_ * 64 * 2048,                                  \
            (char*)A_lds[buf] + p_ * 4096 + ldsb);                                \
      GLD16(Bg + koff_ + (size_t)p_ * 64 * 2048,                                  \
            (char*)B_lds[buf] + p_ * 4096 + ldsb);                                \
    }                                                                             \
  } while (0)

  f32x4 acc[4][4];
#pragma unroll
  for (int i = 0; i < 4; ++i)
#pragma unroll
    for (int j = 0; j < 4; ++j) acc[i][j] = (f32x4){0.f, 0.f, 0.f, 0.f};

  int cur = 0;
  GSTAGE(0, 0);
  for (int ks = 0; ks < 32; ++ks) {
    GSTAGE(cur ^ 1, (ks + 1) & 31);
    asm volatile("s_waitcnt vmcnt(4)" ::: "memory");
    __builtin_amdgcn_s_barrier();
    __builtin_amdgcn_sched_barrier(0);
    const char* Ac = (const char*)A_lds[cur];
    const char* Bc = (const char*)B_lds[cur];
    bf16x8 af[4], bfr[4];
#pragma unroll
    for (int i = 0; i < 4; ++i) {
      int row = wr * 64 + i * 16 + c;
      af[i] = *(const bf16x8*)(Ac + row * 64 + ((g * 16) ^ ((row & 3) << 4)));
    }
#pragma unroll
    for (int j = 0; j < 4; ++j) {
      int row = wc * 64 + j * 16 + c;
      bfr[j] = *(const bf16x8*)(Bc + row * 64 + ((g * 16) ^ ((row & 3) << 4)));
    }
    __builtin_amdgcn_s_setprio(1);
#pragma unroll
    for (int i = 0; i < 4; ++i)
#pragma unroll
      for (int j = 0; j < 4; ++j)
        acc[i][j] = __builtin_amdgcn_mfma_f32_16x16x32_bf16(af[i], bfr[j], acc[i][j], 0, 0, 0);
    __builtin_amdgcn_s_setprio(0);
    asm volatile("s_waitcnt lgkmcnt(0)" ::: "memory");
    __builtin_amdgcn_s_barrier();
    __builtin_amdgcn_sched_barrier(0);
    cur ^= 1;
  }
#undef GSTAGE

  const int sec = n0 >> 10;  // block-uniform: 0=Q, 1=K, 2=V
  const int gq = ((g & 1) << 1) | (g >> 1);  // quad-swap 1<->2 for V n-order
#pragma unroll
  for (int i = 0; i < 4; ++i)
#pragma unroll
    for (int j = 0; j < 4; ++j)
#pragma unroll
      for (int r = 0; r < 4; ++r) {
        int m = m0 + wr * 64 + i * 16 + g * 4 + r;
        int col = n0 + wc * 64 + j * 16 + c;
        int cc = col & 1023;
        u16 v = f2bf(acc[i][j][r]);
        if (sec == 0) Qb[(size_t)m * 1024 + cc] = v;
        else if (sec == 1) Kb[(size_t)m * 1024 + cc] = v;
        else {
          int mq = m0 + wr * 64 + i * 16 + gq * 4 + r;
          Vth[(size_t)cc * 4096 + mq] = v;  // cc = h*64+d, quad-interleaved n
        }
      }
}

// ---------------- out-proj GEMM, 64x64 tiles ----------------
__global__ __launch_bounds__(256) void gemm_out64(const u16* __restrict__ A,
                                                  const u16* __restrict__ Bt,
                                                  float* __restrict__ out,
                                                  const float* __restrict__ bias) {
  __shared__ __align__(16) u16 A_lds[2][64 * 32];
  __shared__ __align__(16) u16 B_lds[2][64 * 32];
  const int tid = threadIdx.x;
  const int l = tid & 63, w = tid >> 6;
  const int g = l >> 4, c = l & 15;
  const int wr = w >> 1, wc = w & 1;
  const int m0 = blockIdx.y * 64, n0 = blockIdx.x * 64;

  const int srow = tid >> 2;
  const u32 sswz = (u32)(((tid & 3) * 16) ^ ((srow & 3) << 4));
  const char* Ag = (const char*)A + (size_t)(m0 + srow) * 2048 + sswz;
  const char* Bg = (const char*)Bt + (size_t)(n0 + srow) * 2048 + sswz;
  const u32 ldsb = (u32)(w * 1024);

#define GSTAGE2(buf, ks_)                                                         \
  do {                                                                            \
    u32 koff_ = (u32)(ks_) * 64;                                                  \
    GLD16(Ag + koff_, (char*)A_lds[buf] + ldsb);                                  \
    GLD16(Bg + koff_, (char*)B_lds[buf] + ldsb);                                  \
  } while (0)

  f32x4 acc[2][2];
#pragma unroll
  for (int i = 0; i < 2; ++i)
#pragma unroll
    for (int j = 0; j < 2; ++j) acc[i][j] = (f32x4){0.f, 0.f, 0.f, 0.f};

  int cur = 0;
  GSTAGE2(0, 0);
  for (int ks = 0; ks < 32; ++ks) {
    GSTAGE2(cur ^ 1, (ks + 1) & 31);
    asm volatile("s_waitcnt vmcnt(2)" ::: "memory");
    __builtin_amdgcn_s_barrier();
    __builtin_amdgcn_sched_barrier(0);
    const char* Ac = (const char*)A_lds[cur];
    const char* Bc = (const char*)B_lds[cur];
    bf16x8 af[2], bfr[2];
#pragma unroll
    for (int i = 0; i < 2; ++i) {
      int row = wr * 32 + i * 16 + c;
      af[i] = *(const bf16x8*)(Ac + row * 64 + ((g * 16) ^ ((row & 3) << 4)));
    }
#pragma unroll
    for (int j = 0; j < 2; ++j) {
      int row = wc * 32 + j * 16 + c;
      bfr[j] = *(const bf16x8*)(Bc + row * 64 + ((g * 16) ^ ((row & 3) << 4)));
    }
    __builtin_amdgcn_s_setprio(1);
#pragma unroll
    for (int i = 0; i < 2; ++i)
#pragma unroll
      for (int j = 0; j < 2; ++j)
        acc[i][j] = __builtin_amdgcn_mfma_f32_16x16x32_bf16(af[i], bfr[j], acc[i][j], 0, 0, 0);
    __builtin_amdgcn_s_setprio(0);
    asm volatile("s_waitcnt lgkmcnt(0)" ::: "memory");
    __builtin_amdgcn_s_barrier();
    __builtin_amdgcn_sched_barrier(0);
    cur ^= 1;
  }
#undef GSTAGE2

#pragma unroll
  for (int i = 0; i < 2; ++i)
#pragma unroll
    for (int j = 0; j < 2; ++j)
#pragma unroll
      for (int r = 0; r < 4; ++r) {
        int m = m0 + wr * 32 + i * 16 + g * 4 + r;
        int col = n0 + wc * 32 + j * 16 + c;
        out[(size_t)m * 1024 + col] = acc[i][j][r] + bias[col];
      }
}

// ---------------- flash attention, swapped-QK^T 32x32, no-max exp2 softmax ----------------
// Early-softmax P-carry: S converted to packed bf16 (pk, 16 u32) in the same phase as
// QK; only pk crosses the stagger boundary. V fragments are single b128 reads thanks to
// the producer-side quad interleave.
template <int SPLIT>
__global__ __launch_bounds__(256, 3) void flash_attn_t(const u16* __restrict__ Qb,
                                                       const u16* __restrict__ Kb,
                                                       const u16* __restrict__ Vt,
                                                       u16* __restrict__ Ob,
                                                       float* __restrict__ Op,
                                                       float* __restrict__ Lp) {
  constexpr int NT = SPLIT ? 32 : 64;  // KV tiles per block
  __shared__ __align__(16) u16 K_lds[2][64 * 64];
  __shared__ __align__(16) u16 V_lds[2][64 * 64];
  const int tid = threadIdx.x;
  const int l = tid & 63, w = tid >> 6;
  const int lq = l & 31, hi = l >> 5;
  const int h = blockIdx.y;
  const int z = SPLIT ? blockIdx.z : 0;
  const int kb = z * 32;  // KV tile base
  const int q = blockIdx.x * 128 + w * 32 + lq;

  bf16x8 qf[4];
  const u16* qrow = Qb + (size_t)q * 1024 + h * 64;
#pragma unroll
  for (int dm = 0; dm < 4; ++dm) qf[dm] = *(const bf16x8*)(qrow + dm * 16 + hi * 8);

  f32x16 ot[2];
#pragma unroll
  for (int a = 0; a < 2; ++a)
#pragma unroll
    for (int r = 0; r < 16; ++r) ot[a][r] = 0.f;
  float lrow = 0.f;
  u32 pkA[16], pkB[16];

  const int srow = tid >> 3;
  const u32 sswz = (u32)(((tid & 7) * 16) ^ ((srow & 7) << 4));
  const char* Kg = (const char*)Kb + ((size_t)srow * 1024 + h * 64) * 2 + sswz;
  const char* Vg = (const char*)Vt + ((size_t)(h * 64 + srow) * 4096) * 2 + sswz;
  const u32 ldsb = (u32)(w * 1024);

  // PV only: O^T[d][q] += V^T . P^T with P from carried pk registers
#define PVONLY(PKP, VSLOT)                                                        \
  {                                                                               \
    const char* Vp_ = (const char*)(VSLOT);                                       \
    __builtin_amdgcn_s_setprio(1);                                                \
    _Pragma("unroll") for (int sti_ = 0; sti_ < 4; ++sti_) {                      \
      u32x4 pw_ = {PKP[sti_ * 4 + 0], PKP[sti_ * 4 + 1], PKP[sti_ * 4 + 2],       \
                   PKP[sti_ * 4 + 3]};                                            \
      bf16x8 pfrag_ = __builtin_bit_cast(bf16x8, pw_);                            \
      const u32 cb_ = (u32)(sti_ * 32 + hi * 16);                                 \
      _Pragma("unroll") for (int a_ = 0; a_ < 2; ++a_) {                          \
        const int rowd_ = a_ * 32 + lq;                                           \
        const u32 rs_ = (u32)(rowd_ * 128), rz_ = (u32)((rowd_ & 7) << 4);        \
        bf16x8 vf_ = *(const bf16x8*)(Vp_ + rs_ + (cb_ ^ rz_));                   \
        ot[a_] = __builtin_amdgcn_mfma_f32_32x32x16_bf16(vf_, pfrag_, ot[a_], 0, 0, 0); \
      }                                                                           \
    }                                                                             \
    __builtin_amdgcn_s_setprio(0);                                                \
  }

  // BODY: stage K(TI+1),V(TI); QK(TI); PV(TI-1, carried PKP); softmax(TI)->PKC
#define BODY(TI, PKC, PKP, DOPREV)                                                \
  {                                                                               \
    const int ti_ = (TI);                                                         \
    const int nxt_ = (ti_ + 1) & (NT - 1);                                        \
    {                                                                             \
      const char* kg_ = Kg + (size_t)(kb + nxt_) * 64 * 2048;                     \
      char* kl_ = (char*)K_lds[nxt_ & 1] + ldsb;                                  \
      GLD16(kg_, kl_);                                                            \
      GLD16(kg_ + 32 * 2048, kl_ + 4096);                                         \
      const char* vg_ = Vg + (size_t)(kb + ti_) * 128;                            \
      char* vl_ = (char*)V_lds[ti_ & 1] + ldsb;                                   \
      GLD16(vg_, vl_);                                                            \
      GLD16(vg_ + (size_t)32 * 8192, vl_ + 4096);                                 \
    }                                                                             \
    asm volatile("s_waitcnt vmcnt(4)" ::: "memory");                              \
    __builtin_amdgcn_s_barrier();                                                 \
    __builtin_amdgcn_sched_barrier(0);                                            \
    const char* Kc_ = (const char*)K_lds[ti_ & 1];                                \
    f32x16 st_[2];                                                                \
    _Pragma("unroll") for (int s_ = 0; s_ < 2; ++s_)                              \
    _Pragma("unroll") for (int r_ = 0; r_ < 16; ++r_) st_[s_][r_] = 0.f;          \
    __builtin_amdgcn_s_setprio(1);                                                \
    _Pragma("unroll") for (int s_ = 0; s_ < 2; ++s_) {                            \
      const int row_ = s_ * 32 + lq;                                              \
      const u32 rs_ = (u32)(row_ * 128), rz_ = (u32)((row_ & 7) << 4);            \
      _Pragma("unroll") for (int dm_ = 0; dm_ < 4; ++dm_) {                       \
        bf16x8 kf_ = *(const bf16x8*)(Kc_ + rs_ + ((u32)(dm_ * 32 + hi * 16) ^ rz_)); \
        st_[s_] = __builtin_amdgcn_mfma_f32_32x32x16_bf16(kf_, qf[dm_], st_[s_], 0, 0, 0); \
      }                                                                           \
    }                                                                             \
    __builtin_amdgcn_s_setprio(0);                                                \
    if (DOPREV) PVONLY(PKP, V_lds[(ti_ - 1) & 1]);                                \
    float rsum_ = 0.f;                                                            \
    _Pragma("unroll") for (int s_ = 0; s_ < 2; ++s_)                              \
    _Pragma("unroll") for (int j_ = 0; j_ < 8; ++j_) {                            \
      float p0_ = __builtin_amdgcn_exp2f(st_[s_][2 * j_]);                        \
      float p1_ = __builtin_amdgcn_exp2f(st_[s_][2 * j_ + 1]);                    \
      rsum_ += p0_ + p1_;                                                         \
      u32 wpk_;                                                                   \
      asm("v_cvt_pk_bf16_f32 %0, %1, %2" : "=v"(wpk_) : "v"(p0_), "v"(p1_));      \
      PKC[s_ * 8 + j_] = wpk_;                                                    \
    }                                                                             \
    lrow += rsum_;                                                                \
    asm volatile("s_waitcnt lgkmcnt(0)" ::: "memory");                            \
    __builtin_amdgcn_s_barrier();                                                 \
    __builtin_amdgcn_sched_barrier(0);                                            \
  }

  {  // prologue: stage K(kb)
    const char* kg0 = Kg + (size_t)kb * 64 * 2048;
    char* kl = (char*)K_lds[0] + ldsb;
    GLD16(kg0, kl);
    GLD16(kg0 + 32 * 2048, kl + 4096);
  }

  BODY(0, pkA, pkA, 0);
  for (int i = 1; i < NT - 1; i += 2) {
    BODY(i, pkB, pkA, 1);
    BODY(i + 1, pkA, pkB, 1);
  }
  BODY(NT - 1, pkB, pkA, 1);
  asm volatile("s_waitcnt vmcnt(0)" ::: "memory");
  __builtin_amdgcn_s_barrier();
  __builtin_amdgcn_sched_barrier(0);
  PVONLY(pkB, V_lds[(NT - 1) & 1]);

#undef BODY
#undef PVONLY

  lrow += __shfl_xor(lrow, 32, 64);
  if constexpr (SPLIT) {
    float* orow = Op + (size_t)z * (4096 * 1024) + (size_t)q * 1024 + h * 64 + hi * 4;
#pragma unroll
    for (int a = 0; a < 2; ++a)
#pragma unroll
      for (int rr = 0; rr < 4; ++rr) {
        float4 fv = {ot[a][rr * 4 + 0], ot[a][rr * 4 + 1], ot[a][rr * 4 + 2],
                     ot[a][rr * 4 + 3]};
        *(float4*)(orow + a * 32 + rr * 8) = fv;
      }
    if (hi == 0) Lp[z * 65536 + h * 4096 + q] = lrow;
  } else {
    float inv = 1.f / lrow;
    u16* orow = Ob + (size_t)q * 1024 + h * 64 + hi * 4;
#pragma unroll
    for (int a = 0; a < 2; ++a)
#pragma unroll
      for (int rr = 0; rr < 4; ++rr) {
        ushort4 o4;
        o4.x = f2bf(ot[a][rr * 4 + 0] * inv);
        o4.y = f2bf(ot[a][rr * 4 + 1] * inv);
        o4.z = f2bf(ot[a][rr * 4 + 2] * inv);
        o4.w = f2bf(ot[a][rr * 4 + 3] * inv);
        *(ushort4*)(orow + a * 32 + rr * 8) = o4;
      }
  }
}

// ---------------- merge KV halves: Ob = (O0+O1)/(L0+L1), f32 -> bf16 ----------------
__global__ __launch_bounds__(256) void merge_halves(const float* __restrict__ O0,
                                                    const float* __restrict__ O1,
                                                    const float* __restrict__ L0,
                                                    const float* __restrict__ L1,
                                                    u16* __restrict__ Ob) {
  int idx = blockIdx.x * 256 + threadIdx.x;  // 8 cols each
  int q = idx >> 7;
  int c0 = (idx & 127) * 8;
  int h = c0 >> 6;
  float inv = 1.f / (L0[h * 4096 + q] + L1[h * 4096 + q]);
  size_t off = (size_t)q * 1024 + c0;
  float4 a0 = *(const float4*)(O0 + off), a1 = *(const float4*)(O0 + off + 4);
  float4 b0 = *(const float4*)(O1 + off), b1 = *(const float4*)(O1 + off + 4);
  ushort4 o0, o1;
  o0.x = f2bf((a0.x + b0.x) * inv);
  o0.y = f2bf((a0.y + b0.y) * inv);
  o0.z = f2bf((a0.z + b0.z) * inv);
  o0.w = f2bf((a0.w + b0.w) * inv);
  o1.x = f2bf((a1.x + b1.x) * inv);
  o1.y = f2bf((a1.y + b1.y) * inv);
  o1.z = f2bf((a1.z + b1.z) * inv);
  o1.w = f2bf((a1.w + b1.w) * inv);
  *(ushort4*)(Ob + off) = o0;
  *(ushort4*)(Ob + off + 4) = o1;
}

extern "C" void kernel_launch(void* const* d_in, const int* in_sizes, int n_in,
                              void* d_out, int out_size, void* d_ws, size_t ws_size,
                              hipStream_t stream) {
  const float* x = (const float*)d_in[0];
  const float* Wq = (const float*)d_in[1];
  const float* Wk = (const float*)d_in[2];
  const float* Wv = (const float*)d_in[3];
  const float* Wo = (const float*)d_in[4];
  const float* bo = (const float*)d_in[5];
  float* out = (float*)d_out;

  char* ws = (char*)d_ws;
  u16* xb  = (u16*)(ws);                  // 8 MB (dead after gemm_qkv; reused as ObM)
  u16* Wqt = (u16*)(ws + (8u << 20));     // 2 MB  [Wqt|Wkt|Wvt] contiguous
  u16* Wot = (u16*)(ws + (14u << 20));    // 2 MB
  u16* Qb  = (u16*)(ws + (16u << 20));    // 8 MB
  u16* Kbf = (u16*)(ws + (24u << 20));    // 8 MB
  u16* Vth = (u16*)(ws + (32u << 20));    // 8 MB  [h][64][n] (quad-interleaved n)
  u16* Ob  = (u16*)(ws + (40u << 20));    // 8 MB (fallback path output)
  float* Op = (float*)(ws + (40u << 20)); // 32 MB (split path: 2x f32 partials)
  float* Lp = (float*)(ws + (72u << 20)); // 512 KB (2x16x4096 f32)
  u16* Wkt = Wqt + (1u << 20);
  u16* Wvt = Wqt + (2u << 20);

  const bool split = ws_size >= ((73u << 20) + (1u << 19));

  cvt_bf16_kernel<<<2048, 256, 0, stream>>>(x, xb, 4096 * 1024);
  transpose4<<<dim3(16, 16, 4), 256, 0, stream>>>(Wq, Wk, Wv, Wo, Wqt, Wkt, Wvt, Wot);
  gemm_qkv<<<dim3(24, 32), 256, 0, stream>>>(xb, Wqt, Qb, Kbf, Vth);

  if (split) {
    flash_attn_t<1><<<dim3(32, 16, 2), 256, 0, stream>>>(Qb, Kbf, Vth, nullptr, Op, Lp);
    u16* ObM = (u16*)ws;  // reuse xb region
    merge_halves<<<2048, 256, 0, stream>>>(Op, Op + (1u << 22), Lp, Lp + 65536, ObM);
    gemm_out64<<<dim3(16, 64), 256, 0, stream>>>(ObM, Wot, out, bo);
  } else {
    flash_attn_t<0><<<dim3(32, 16, 1), 256, 0, stream>>>(Qb, Kbf, Vth, Ob, nullptr, nullptr);
    gemm_out64<<<dim3(16, 64), 256, 0, stream>>>(Ob, Wot, out, bo);
  }
}

// Round 6
// 188.352 us; speedup vs baseline: 1.1034x; 1.0700x over previous
//
#include <hip/hip_runtime.h>
#include <stdint.h>

#define NH 16
#define NN 4096

typedef __attribute__((ext_vector_type(8))) short bf16x8;
typedef __attribute__((ext_vector_type(4))) short bf16x4;
typedef __attribute__((ext_vector_type(4))) float f32x4;
typedef __attribute__((ext_vector_type(16))) float f32x16;
typedef unsigned short u16;
typedef unsigned int u32;
typedef __attribute__((ext_vector_type(4))) u32 u32x4;

__device__ __forceinline__ u16 f2bf(float f) {
  u32 u = __float_as_uint(f);
  return (u16)((u + 0x7FFFu + ((u >> 16) & 1u)) >> 16);
}

#define GLD16(gp, lp)                                              \
  __builtin_amdgcn_global_load_lds(                                \
      (__attribute__((address_space(1))) void*)(gp),               \
      (__attribute__((address_space(3))) void*)(lp), 16, 0, 0)

// ---------------- elementwise f32 -> bf16 ----------------
__global__ __launch_bounds__(256) void cvt_bf16_kernel(const float* __restrict__ src,
                                                       u16* __restrict__ dst, int n) {
  int i = (blockIdx.x * blockDim.x + threadIdx.x) * 8;
  if (i >= n) return;
  float4 a = *(const float4*)(src + i);
  float4 b = *(const float4*)(src + i + 4);
  uint4 o;
  o.x = (u32)f2bf(a.x) | ((u32)f2bf(a.y) << 16);
  o.y = (u32)f2bf(a.z) | ((u32)f2bf(a.w) << 16);
  o.z = (u32)f2bf(b.x) | ((u32)f2bf(b.y) << 16);
  o.w = (u32)f2bf(b.z) | ((u32)f2bf(b.w) << 16);
  *(uint4*)(dst + i) = o;
}

// ---------------- fused 4x transpose + cvt: W[k][n] f32 -> Wt[n][k] bf16 ----------------
__global__ __launch_bounds__(256) void transpose4(const float* __restrict__ Wq,
                                                  const float* __restrict__ Wk,
                                                  const float* __restrict__ Wv,
                                                  const float* __restrict__ Wo,
                                                  u16* __restrict__ Wqt, u16* __restrict__ Wkt,
                                                  u16* __restrict__ Wvt, u16* __restrict__ Wot) {
  __shared__ float tile[64][65];
  const float* src;
  u16* dst;
  float scale = 1.0f;
  int z = blockIdx.z;
  if (z == 0) { src = Wq; dst = Wqt; scale = 0.125f * 1.4426950408889634f; }
  else if (z == 1) { src = Wk; dst = Wkt; }
  else if (z == 2) { src = Wv; dst = Wvt; }
  else { src = Wo; dst = Wot; }
  int tx = threadIdx.x & 63, ty = threadIdx.x >> 6;
  int c0 = blockIdx.x * 64, r0 = blockIdx.y * 64;
#pragma unroll
  for (int i = ty; i < 64; i += 4)
    tile[i][tx] = src[(size_t)(r0 + i) * 1024 + c0 + tx];
  __syncthreads();
#pragma unroll
  for (int i = ty; i < 64; i += 4)
    dst[(size_t)(c0 + i) * 1024 + r0 + tx] = f2bf(tile[tx][i] * scale);
}

// ---------------- fused QKV GEMM: [4096][1024] @ Wt[3072][1024]^T ----------------
// V (sec==2) is stored with n-within-16 quads interleaved [0,2,1,3] so flash PV
// can read each A-fragment as a single b128.
__global__ __launch_bounds__(256) void gemm_qkv(const u16* __restrict__ A,
                                                const u16* __restrict__ Bt,
                                                u16* __restrict__ Qb, u16* __restrict__ Kb,
                                                u16* __restrict__ Vth) {
  __shared__ __align__(16) u16 A_lds[2][128 * 32];
  __shared__ __align__(16) u16 B_lds[2][128 * 32];
  const int tid = threadIdx.x;
  const int l = tid & 63, w = tid >> 6;
  const int g = l >> 4, c = l & 15;
  const int wr = w >> 1, wc = w & 1;
  const int m0 = blockIdx.y * 128, n0 = blockIdx.x * 128;

  const int srow = tid >> 2;
  const u32 sswz = (u32)(((tid & 3) * 16) ^ ((srow & 3) << 4));
  const char* Ag = (const char*)A + (size_t)(m0 + srow) * 2048 + sswz;
  const char* Bg = (const char*)Bt + (size_t)(n0 + srow) * 2048 + sswz;
  const u32 ldsb = (u32)(w * 1024);

#define GSTAGE(buf, ks_)                                                          \
  do {                                                                            \
    u32 koff_ = (u32)(ks_) * 64;                                                  \
    _Pragma("unroll") for (int p_ = 0; p_ < 2; ++p_) {                            \
      GLD16(Ag + koff_ + (size_t)p_ * 64 * 2048,                                  \
            (char*)A_lds[buf] + p_ * 4096 + ldsb);                                \
      GLD16(Bg + koff_ + (size_t)p_ * 64 * 2048,                                  \
            (char*)B_lds[buf] + p_ * 4096 + ldsb);                                \
    }                                                                             \
  } while (0)

  f32x4 acc[4][4];
#pragma unroll
  for (int i = 0; i < 4; ++i)
#pragma unroll
    for (int j = 0; j < 4; ++j) acc[i][j] = (f32x4){0.f, 0.f, 0.f, 0.f};

  int cur = 0;
  GSTAGE(0, 0);
  for (int ks = 0; ks < 32; ++ks) {
    GSTAGE(cur ^ 1, (ks + 1) & 31);
    asm volatile("s_waitcnt vmcnt(4)" ::: "memory");
    __builtin_amdgcn_s_barrier();
    __builtin_amdgcn_sched_barrier(0);
    const char* Ac = (const char*)A_lds[cur];
    const char* Bc = (const char*)B_lds[cur];
    bf16x8 af[4], bfr[4];
#pragma unroll
    for (int i = 0; i < 4; ++i) {
      int row = wr * 64 + i * 16 + c;
      af[i] = *(const bf16x8*)(Ac + row * 64 + ((g * 16) ^ ((row & 3) << 4)));
    }
#pragma unroll
    for (int j = 0; j < 4; ++j) {
      int row = wc * 64 + j * 16 + c;
      bfr[j] = *(const bf16x8*)(Bc + row * 64 + ((g * 16) ^ ((row & 3) << 4)));
    }
    __builtin_amdgcn_s_setprio(1);
#pragma unroll
    for (int i = 0; i < 4; ++i)
#pragma unroll
      for (int j = 0; j < 4; ++j)
        acc[i][j] = __builtin_amdgcn_mfma_f32_16x16x32_bf16(af[i], bfr[j], acc[i][j], 0, 0, 0);
    __builtin_amdgcn_s_setprio(0);
    asm volatile("s_waitcnt lgkmcnt(0)" ::: "memory");
    __builtin_amdgcn_s_barrier();
    __builtin_amdgcn_sched_barrier(0);
    cur ^= 1;
  }
#undef GSTAGE

  const int sec = n0 >> 10;  // block-uniform: 0=Q, 1=K, 2=V
  const int gq = ((g & 1) << 1) | (g >> 1);  // quad-swap 1<->2 for V n-order
#pragma unroll
  for (int i = 0; i < 4; ++i)
#pragma unroll
    for (int j = 0; j < 4; ++j)
#pragma unroll
      for (int r = 0; r < 4; ++r) {
        int m = m0 + wr * 64 + i * 16 + g * 4 + r;
        int col = n0 + wc * 64 + j * 16 + c;
        int cc = col & 1023;
        u16 v = f2bf(acc[i][j][r]);
        if (sec == 0) Qb[(size_t)m * 1024 + cc] = v;
        else if (sec == 1) Kb[(size_t)m * 1024 + cc] = v;
        else {
          int mq = m0 + wr * 64 + i * 16 + gq * 4 + r;
          Vth[(size_t)cc * 4096 + mq] = v;  // cc = h*64+d, quad-interleaved n
        }
      }
}

// ---------------- out-proj GEMM, 64x64 tiles ----------------
__global__ __launch_bounds__(256) void gemm_out64(const u16* __restrict__ A,
                                                  const u16* __restrict__ Bt,
                                                  float* __restrict__ out,
                                                  const float* __restrict__ bias) {
  __shared__ __align__(16) u16 A_lds[2][64 * 32];
  __shared__ __align__(16) u16 B_lds[2][64 * 32];
  const int tid = threadIdx.x;
  const int l = tid & 63, w = tid >> 6;
  const int g = l >> 4, c = l & 15;
  const int wr = w >> 1, wc = w & 1;
  const int m0 = blockIdx.y * 64, n0 = blockIdx.x * 64;

  const int srow = tid >> 2;
  const u32 sswz = (u32)(((tid & 3) * 16) ^ ((srow & 3) << 4));
  const char* Ag = (const char*)A + (size_t)(m0 + srow) * 2048 + sswz;
  const char* Bg = (const char*)Bt + (size_t)(n0 + srow) * 2048 + sswz;
  const u32 ldsb = (u32)(w * 1024);

#define GSTAGE2(buf, ks_)                                                         \
  do {                                                                            \
    u32 koff_ = (u32)(ks_) * 64;                                                  \
    GLD16(Ag + koff_, (char*)A_lds[buf] + ldsb);                                  \
    GLD16(Bg + koff_, (char*)B_lds[buf] + ldsb);                                  \
  } while (0)

  f32x4 acc[2][2];
#pragma unroll
  for (int i = 0; i < 2; ++i)
#pragma unroll
    for (int j = 0; j < 2; ++j) acc[i][j] = (f32x4){0.f, 0.f, 0.f, 0.f};

  int cur = 0;
  GSTAGE2(0, 0);
  for (int ks = 0; ks < 32; ++ks) {
    GSTAGE2(cur ^ 1, (ks + 1) & 31);
    asm volatile("s_waitcnt vmcnt(2)" ::: "memory");
    __builtin_amdgcn_s_barrier();
    __builtin_amdgcn_sched_barrier(0);
    const char* Ac = (const char*)A_lds[cur];
    const char* Bc = (const char*)B_lds[cur];
    bf16x8 af[2], bfr[2];
#pragma unroll
    for (int i = 0; i < 2; ++i) {
      int row = wr * 32 + i * 16 + c;
      af[i] = *(const bf16x8*)(Ac + row * 64 + ((g * 16) ^ ((row & 3) << 4)));
    }
#pragma unroll
    for (int j = 0; j < 2; ++j) {
      int row = wc * 32 + j * 16 + c;
      bfr[j] = *(const bf16x8*)(Bc + row * 64 + ((g * 16) ^ ((row & 3) << 4)));
    }
    __builtin_amdgcn_s_setprio(1);
#pragma unroll
    for (int i = 0; i < 2; ++i)
#pragma unroll
      for (int j = 0; j < 2; ++j)
        acc[i][j] = __builtin_amdgcn_mfma_f32_16x16x32_bf16(af[i], bfr[j], acc[i][j], 0, 0, 0);
    __builtin_amdgcn_s_setprio(0);
    asm volatile("s_waitcnt lgkmcnt(0)" ::: "memory");
    __builtin_amdgcn_s_barrier();
    __builtin_amdgcn_sched_barrier(0);
    cur ^= 1;
  }
#undef GSTAGE2

#pragma unroll
  for (int i = 0; i < 2; ++i)
#pragma unroll
    for (int j = 0; j < 2; ++j)
#pragma unroll
      for (int r = 0; r < 4; ++r) {
        int m = m0 + wr * 32 + i * 16 + g * 4 + r;
        int col = n0 + wc * 32 + j * 16 + c;
        out[(size_t)m * 1024 + col] = acc[i][j][r] + bias[col];
      }
}

// ---------------- flash attention, swapped-QK^T 32x32, no-max exp2 softmax ----------------
// 64 q-rows per wave (two 32-row groups): K/V fragments read from LDS ONCE feed TWO
// MFMAs each (2x LDS arithmetic intensity). Early-softmax P-carry across the stagger.
template <int SPLIT>
__global__ __launch_bounds__(256, 2) void flash_attn_t(const u16* __restrict__ Qb,
                                                       const u16* __restrict__ Kb,
                                                       const u16* __restrict__ Vt,
                                                       u16* __restrict__ Ob,
                                                       float* __restrict__ Op,
                                                       float* __restrict__ Lp) {
  constexpr int NT = SPLIT ? 32 : 64;  // KV tiles per block
  __shared__ __align__(16) u16 K_lds[2][64 * 64];
  __shared__ __align__(16) u16 V_lds[2][64 * 64];
  const int tid = threadIdx.x;
  const int l = tid & 63, w = tid >> 6;
  const int lq = l & 31, hi = l >> 5;
  const int h = blockIdx.y;
  const int z = SPLIT ? blockIdx.z : 0;
  const int kb = z * 32;                      // KV tile base (split half)
  const int qb = blockIdx.x * 256 + w * 64;   // wave's 64-row q base
  const int q0 = qb + lq, q1 = qb + 32 + lq;

  bf16x8 qf0[4], qf1[4];
  {
    const u16* qr0 = Qb + (size_t)q0 * 1024 + h * 64;
    const u16* qr1 = Qb + (size_t)q1 * 1024 + h * 64;
#pragma unroll
    for (int dm = 0; dm < 4; ++dm) {
      qf0[dm] = *(const bf16x8*)(qr0 + dm * 16 + hi * 8);
      qf1[dm] = *(const bf16x8*)(qr1 + dm * 16 + hi * 8);
    }
  }

  f32x16 ot0[2], ot1[2];
#pragma unroll
  for (int a = 0; a < 2; ++a)
#pragma unroll
    for (int r = 0; r < 16; ++r) { ot0[a][r] = 0.f; ot1[a][r] = 0.f; }
  float lrow0 = 0.f, lrow1 = 0.f;
  u32 pkA0[16], pkA1[16], pkB0[16], pkB1[16];

  const int srow = tid >> 3;
  const u32 sswz = (u32)(((tid & 7) * 16) ^ ((srow & 7) << 4));
  const char* Kg = (const char*)Kb + ((size_t)srow * 1024 + h * 64) * 2 + sswz;
  const char* Vg = (const char*)Vt + ((size_t)(h * 64 + srow) * 4096) * 2 + sswz;
  const u32 ldsb = (u32)(w * 1024);

  // PV only: each V fragment read once, feeds both q-groups' accumulators
#define PVONLY(P0, P1, VSLOT)                                                     \
  {                                                                               \
    const char* Vp_ = (const char*)(VSLOT);                                       \
    __builtin_amdgcn_s_setprio(1);                                                \
    _Pragma("unroll") for (int sti_ = 0; sti_ < 4; ++sti_) {                      \
      u32x4 pw0_ = {P0[sti_ * 4 + 0], P0[sti_ * 4 + 1], P0[sti_ * 4 + 2],         \
                    P0[sti_ * 4 + 3]};                                            \
      u32x4 pw1_ = {P1[sti_ * 4 + 0], P1[sti_ * 4 + 1], P1[sti_ * 4 + 2],         \
                    P1[sti_ * 4 + 3]};                                            \
      bf16x8 pf0_ = __builtin_bit_cast(bf16x8, pw0_);                             \
      bf16x8 pf1_ = __builtin_bit_cast(bf16x8, pw1_);                             \
      const u32 cb_ = (u32)(sti_ * 32 + hi * 16);                                 \
      _Pragma("unroll") for (int a_ = 0; a_ < 2; ++a_) {                          \
        const int rowd_ = a_ * 32 + lq;                                           \
        const u32 rs_ = (u32)(rowd_ * 128), rz_ = (u32)((rowd_ & 7) << 4);        \
        bf16x8 vf_ = *(const bf16x8*)(Vp_ + rs_ + (cb_ ^ rz_));                   \
        ot0[a_] = __builtin_amdgcn_mfma_f32_32x32x16_bf16(vf_, pf0_, ot0[a_], 0, 0, 0); \
        ot1[a_] = __builtin_amdgcn_mfma_f32_32x32x16_bf16(vf_, pf1_, ot1[a_], 0, 0, 0); \
      }                                                                           \
    }                                                                             \
    __builtin_amdgcn_s_setprio(0);                                                \
  }

  // BODY: stage K(TI+1),V(TI); QK(TI) both groups (kf shared); PV(TI-1); softmax->pk
#define BODY(TI, C0, C1, P0, P1, DOPREV)                                          \
  {                                                                               \
    const int ti_ = (TI);                                                         \
    const int nxt_ = (ti_ + 1) & (NT - 1);                                        \
    {                                                                             \
      const char* kg_ = Kg + (size_t)(kb + nxt_) * 64 * 2048;                     \
      char* kl_ = (char*)K_lds[nxt_ & 1] + ldsb;                                  \
      GLD16(kg_, kl_);                                                            \
      GLD16(kg_ + 32 * 2048, kl_ + 4096);                                         \
      const char* vg_ = Vg + (size_t)(kb + ti_) * 128;                            \
      char* vl_ = (char*)V_lds[ti_ & 1] + ldsb;                                   \
      GLD16(vg_, vl_);                                                            \
      GLD16(vg_ + (size_t)32 * 8192, vl_ + 4096);                                 \
    }                                                                             \
    asm volatile("s_waitcnt vmcnt(4)" ::: "memory");                              \
    __builtin_amdgcn_s_barrier();                                                 \
    __builtin_amdgcn_sched_barrier(0);                                            \
    const char* Kc_ = (const char*)K_lds[ti_ & 1];                                \
    f32x16 st0_[2], st1_[2];                                                      \
    _Pragma("unroll") for (int s_ = 0; s_ < 2; ++s_)                              \
    _Pragma("unroll") for (int r_ = 0; r_ < 16; ++r_) {                           \
      st0_[s_][r_] = 0.f;                                                         \
      st1_[s_][r_] = 0.f;                                                         \
    }                                                                             \
    __builtin_amdgcn_s_setprio(1);                                                \
    _Pragma("unroll") for (int s_ = 0; s_ < 2; ++s_) {                            \
      const int row_ = s_ * 32 + lq;                                              \
      const u32 rs_ = (u32)(row_ * 128), rz_ = (u32)((row_ & 7) << 4);            \
      _Pragma("unroll") for (int dm_ = 0; dm_ < 4; ++dm_) {                       \
        bf16x8 kf_ = *(const bf16x8*)(Kc_ + rs_ + ((u32)(dm_ * 32 + hi * 16) ^ rz_)); \
        st0_[s_] = __builtin_amdgcn_mfma_f32_32x32x16_bf16(kf_, qf0[dm_], st0_[s_], 0, 0, 0); \
        st1_[s_] = __builtin_amdgcn_mfma_f32_32x32x16_bf16(kf_, qf1[dm_], st1_[s_], 0, 0, 0); \
      }                                                                           \
    }                                                                             \
    __builtin_amdgcn_s_setprio(0);                                                \
    if (DOPREV) PVONLY(P0, P1, V_lds[(ti_ - 1) & 1]);                             \
    float rs0_ = 0.f, rs1_ = 0.f;                                                 \
    _Pragma("unroll") for (int s_ = 0; s_ < 2; ++s_)                              \
    _Pragma("unroll") for (int j_ = 0; j_ < 8; ++j_) {                            \
      float a0_ = __builtin_amdgcn_exp2f(st0_[s_][2 * j_]);                       \
      float a1_ = __builtin_amdgcn_exp2f(st0_[s_][2 * j_ + 1]);                   \
      rs0_ += a0_ + a1_;                                                          \
      u32 wp0_;                                                                   \
      asm("v_cvt_pk_bf16_f32 %0, %1, %2" : "=v"(wp0_) : "v"(a0_), "v"(a1_));      \
      C0[s_ * 8 + j_] = wp0_;                                                     \
      float b0_ = __builtin_amdgcn_exp2f(st1_[s_][2 * j_]);                       \
      float b1_ = __builtin_amdgcn_exp2f(st1_[s_][2 * j_ + 1]);                   \
      rs1_ += b0_ + b1_;                                                          \
      u32 wp1_;                                                                   \
      asm("v_cvt_pk_bf16_f32 %0, %1, %2" : "=v"(wp1_) : "v"(b0_), "v"(b1_));      \
      C1[s_ * 8 + j_] = wp1_;                                                     \
    }                                                                             \
    lrow0 += rs0_;                                                                \
    lrow1 += rs1_;                                                                \
    asm volatile("s_waitcnt lgkmcnt(0)" ::: "memory");                            \
    __builtin_amdgcn_s_barrier();                                                 \
    __builtin_amdgcn_sched_barrier(0);                                            \
  }

  {  // prologue: stage K(kb)
    const char* kg0 = Kg + (size_t)kb * 64 * 2048;
    char* kl = (char*)K_lds[0] + ldsb;
    GLD16(kg0, kl);
    GLD16(kg0 + 32 * 2048, kl + 4096);
  }

  BODY(0, pkA0, pkA1, pkA0, pkA1, 0);
  for (int i = 1; i < NT - 1; i += 2) {
    BODY(i, pkB0, pkB1, pkA0, pkA1, 1);
    BODY(i + 1, pkA0, pkA1, pkB0, pkB1, 1);
  }
  BODY(NT - 1, pkB0, pkB1, pkA0, pkA1, 1);
  asm volatile("s_waitcnt vmcnt(0)" ::: "memory");
  __builtin_amdgcn_s_barrier();
  __builtin_amdgcn_sched_barrier(0);
  PVONLY(pkB0, pkB1, V_lds[(NT - 1) & 1]);

#undef BODY
#undef PVONLY

  lrow0 += __shfl_xor(lrow0, 32, 64);
  lrow1 += __shfl_xor(lrow1, 32, 64);
  if constexpr (SPLIT) {
    float* or0 = Op + (size_t)z * (4096 * 1024) + (size_t)q0 * 1024 + h * 64 + hi * 4;
    float* or1 = Op + (size_t)z * (4096 * 1024) + (size_t)q1 * 1024 + h * 64 + hi * 4;
#pragma unroll
    for (int a = 0; a < 2; ++a)
#pragma unroll
      for (int rr = 0; rr < 4; ++rr) {
        float4 f0 = {ot0[a][rr * 4 + 0], ot0[a][rr * 4 + 1], ot0[a][rr * 4 + 2],
                     ot0[a][rr * 4 + 3]};
        *(float4*)(or0 + a * 32 + rr * 8) = f0;
        float4 f1 = {ot1[a][rr * 4 + 0], ot1[a][rr * 4 + 1], ot1[a][rr * 4 + 2],
                     ot1[a][rr * 4 + 3]};
        *(float4*)(or1 + a * 32 + rr * 8) = f1;
      }
    if (hi == 0) {
      Lp[z * 65536 + h * 4096 + q0] = lrow0;
      Lp[z * 65536 + h * 4096 + q1] = lrow1;
    }
  } else {
    float inv0 = 1.f / lrow0, inv1 = 1.f / lrow1;
    u16* or0 = Ob + (size_t)q0 * 1024 + h * 64 + hi * 4;
    u16* or1 = Ob + (size_t)q1 * 1024 + h * 64 + hi * 4;
#pragma unroll
    for (int a = 0; a < 2; ++a)
#pragma unroll
      for (int rr = 0; rr < 4; ++rr) {
        ushort4 o4;
        o4.x = f2bf(ot0[a][rr * 4 + 0] * inv0);
        o4.y = f2bf(ot0[a][rr * 4 + 1] * inv0);
        o4.z = f2bf(ot0[a][rr * 4 + 2] * inv0);
        o4.w = f2bf(ot0[a][rr * 4 + 3] * inv0);
        *(ushort4*)(or0 + a * 32 + rr * 8) = o4;
        o4.x = f2bf(ot1[a][rr * 4 + 0] * inv1);
        o4.y = f2bf(ot1[a][rr * 4 + 1] * inv1);
        o4.z = f2bf(ot1[a][rr * 4 + 2] * inv1);
        o4.w = f2bf(ot1[a][rr * 4 + 3] * inv1);
        *(ushort4*)(or1 + a * 32 + rr * 8) = o4;
      }
  }
}

// ---------------- merge KV halves: Ob = (O0+O1)/(L0+L1), f32 -> bf16 ----------------
__global__ __launch_bounds__(256) void merge_halves(const float* __restrict__ O0,
                                                    const float* __restrict__ O1,
                                                    const float* __restrict__ L0,
                                                    const float* __restrict__ L1,
                                                    u16* __restrict__ Ob) {
  int idx = blockIdx.x * 256 + threadIdx.x;  // 8 cols each
  int q = idx >> 7;
  int c0 = (idx & 127) * 8;
  int h = c0 >> 6;
  float inv = 1.f / (L0[h * 4096 + q] + L1[h * 4096 + q]);
  size_t off = (size_t)q * 1024 + c0;
  float4 a0 = *(const float4*)(O0 + off), a1 = *(const float4*)(O0 + off + 4);
  float4 b0 = *(const float4*)(O1 + off), b1 = *(const float4*)(O1 + off + 4);
  ushort4 o0, o1;
  o0.x = f2bf((a0.x + b0.x) * inv);
  o0.y = f2bf((a0.y + b0.y) * inv);
  o0.z = f2bf((a0.z + b0.z) * inv);
  o0.w = f2bf((a0.w + b0.w) * inv);
  o1.x = f2bf((a1.x + b1.x) * inv);
  o1.y = f2bf((a1.y + b1.y) * inv);
  o1.z = f2bf((a1.z + b1.z) * inv);
  o1.w = f2bf((a1.w + b1.w) * inv);
  *(ushort4*)(Ob + off) = o0;
  *(ushort4*)(Ob + off + 4) = o1;
}

extern "C" void kernel_launch(void* const* d_in, const int* in_sizes, int n_in,
                              void* d_out, int out_size, void* d_ws, size_t ws_size,
                              hipStream_t stream) {
  const float* x = (const float*)d_in[0];
  const float* Wq = (const float*)d_in[1];
  const float* Wk = (const float*)d_in[2];
  const float* Wv = (const float*)d_in[3];
  const float* Wo = (const float*)d_in[4];
  const float* bo = (const float*)d_in[5];
  float* out = (float*)d_out;

  char* ws = (char*)d_ws;
  u16* xb  = (u16*)(ws);                  // 8 MB (dead after gemm_qkv; reused as ObM)
  u16* Wqt = (u16*)(ws + (8u << 20));     // 2 MB  [Wqt|Wkt|Wvt] contiguous
  u16* Wot = (u16*)(ws + (14u << 20));    // 2 MB
  u16* Qb  = (u16*)(ws + (16u << 20));    // 8 MB
  u16* Kbf = (u16*)(ws + (24u << 20));    // 8 MB
  u16* Vth = (u16*)(ws + (32u << 20));    // 8 MB  [h][64][n] (quad-interleaved n)
  u16* Ob  = (u16*)(ws + (40u << 20));    // 8 MB (fallback path output)
  float* Op = (float*)(ws + (40u << 20)); // 32 MB (split path: 2x f32 partials)
  float* Lp = (float*)(ws + (72u << 20)); // 512 KB (2x16x4096 f32)
  u16* Wkt = Wqt + (1u << 20);
  u16* Wvt = Wqt + (2u << 20);

  const bool split = ws_size >= ((73u << 20) + (1u << 19));

  cvt_bf16_kernel<<<2048, 256, 0, stream>>>(x, xb, 4096 * 1024);
  transpose4<<<dim3(16, 16, 4), 256, 0, stream>>>(Wq, Wk, Wv, Wo, Wqt, Wkt, Wvt, Wot);
  gemm_qkv<<<dim3(24, 32), 256, 0, stream>>>(xb, Wqt, Qb, Kbf, Vth);

  if (split) {
    flash_attn_t<1><<<dim3(16, 16, 2), 256, 0, stream>>>(Qb, Kbf, Vth, nullptr, Op, Lp);
    u16* ObM = (u16*)ws;  // reuse xb region
    merge_halves<<<2048, 256, 0, stream>>>(Op, Op + (1u << 22), Lp, Lp + 65536, ObM);
    gemm_out64<<<dim3(16, 64), 256, 0, stream>>>(ObM, Wot, out, bo);
  } else {
    flash_attn_t<0><<<dim3(16, 16, 1), 256, 0, stream>>>(Qb, Kbf, Vth, Ob, nullptr, nullptr);
    gemm_out64<<<dim3(16, 64), 256, 0, stream>>>(Ob, Wot, out, bo);
  }
}